// Round 13
// baseline (49980.792 us; speedup 1.0000x reference)
//
#include <hip/hip_runtime.h>
#include <stdint.h>

#define L4   250   // chase chunk length
#define GRP  50    // chunks per map-composition group
#define PF   32    // feat prefetch depth in k_chain
#define CSZ  256   // checkpoint interval (power of 2)
#define CSB  8     // log2(CSZ)

// DPP row_ror:K — dst lane i reads src lane (i-K)&15 within its row of 16.
// Direction HW-validated bit-exact (absmax 0) in prior rounds.
template<int K>
__device__ __forceinline__ float rotr(float x) {
  return __int_as_float(__builtin_amdgcn_mov_dpp(__float_as_int(x), 0x120 + K, 0xF, 0xF, false));
}

// Full 16-candidate exact step (used by throughput kernel k_fv).
// Lane layout: n = lane&15, lane holds fv[n]; trr[k] = tr[n][(n-k)&15].
// fp32 max over 16 finite values is order-independent -> bit-identical to
// the reference's jnp.max regardless of tree shape.
__device__ __forceinline__ float vstep(float fv, const float* __restrict__ trr) {
  float c0  = fv           + trr[0];
  float c1  = rotr<1 >(fv) + trr[1];
  float c2  = rotr<2 >(fv) + trr[2];
  float c3  = rotr<3 >(fv) + trr[3];
  float c4  = rotr<4 >(fv) + trr[4];
  float c5  = rotr<5 >(fv) + trr[5];
  float c6  = rotr<6 >(fv) + trr[6];
  float c7  = rotr<7 >(fv) + trr[7];
  float c8  = rotr<8 >(fv) + trr[8];
  float c9  = rotr<9 >(fv) + trr[9];
  float c10 = rotr<10>(fv) + trr[10];
  float c11 = rotr<11>(fv) + trr[11];
  float c12 = rotr<12>(fv) + trr[12];
  float c13 = rotr<13>(fv) + trr[13];
  float c14 = rotr<14>(fv) + trr[14];
  float c15 = rotr<15>(fv) + trr[15];
  float t0 = fmaxf(fmaxf(c0,  c1),  c2);
  float t1 = fmaxf(fmaxf(c3,  c4),  c5);
  float t2 = fmaxf(fmaxf(c6,  c7),  c8);
  float t3 = fmaxf(fmaxf(c9,  c10), c11);
  float t4 = fmaxf(fmaxf(c12, c13), c14);
  float u0 = fmaxf(fmaxf(t0, t1), t2);
  float u1 = fmaxf(fmaxf(t3, t4), c15);
  return fmaxf(u0, u1);
}

// Full 16-rotation exact step — FORCED ASM (r13). Rationale: r12's cost model
// shows cross-lane hops cost ~16 cy vs ~6 for plain VALU on the solo-wave
// dependent chain; split-8 has 3 cross-lane hops (candidate add_dpp,
// permlane32_swap, tail add_dpp), 16-rot has ONE (candidate add_dpp) — its
// r5 failure was compiler codegen (unfused movs/auto-nops), never tested as
// forced asm. 25 instructions, ZERO s_nops.
// Lane layout: ALL lanes hold fv[n], n = lane&15 (4x replicated rows);
// trr[k] = tr[n][(n-k)&15]; c_k = fv[(n-k)&15] + tr[n][(n-k)&15] covers all
// 16 p exactly once (r5 HW-validated, absmax 0). Tree: 5+2 v_max3 + v_max,
// order-independent fp32 max -> bit-identical to reference jnp.max.
// Tail: fv = m + fb, plain add (no redistribute needed in this layout).
// Hazards: only DPP reads are of fv, last written by the PREVIOUS step's
// final plain add; the interposed c0 plain add (1 full wave64 VALU) provides
// the 2 wait states — the exact pattern r10/r12 proved sufficient (absmax 0).
__device__ __forceinline__ float step16_asm(float fvh,
    float t0, float t1, float t2, float t3,
    float t4, float t5, float t6, float t7,
    float t8, float t9, float t10, float t11,
    float t12, float t13, float t14, float t15, float fb) {
  float c0, c1, c2, c3, c4, c5, c6, c7, c8, c9, c10, c11, c12, c13, c14, c15;
  asm volatile(
    "v_add_f32 %[c0], %[fv], %[t0]\n\t"
    "v_add_f32_dpp %[c1],  %[fv], %[t1]  row_ror:1  row_mask:0xf bank_mask:0xf\n\t"
    "v_add_f32_dpp %[c2],  %[fv], %[t2]  row_ror:2  row_mask:0xf bank_mask:0xf\n\t"
    "v_add_f32_dpp %[c3],  %[fv], %[t3]  row_ror:3  row_mask:0xf bank_mask:0xf\n\t"
    "v_add_f32_dpp %[c4],  %[fv], %[t4]  row_ror:4  row_mask:0xf bank_mask:0xf\n\t"
    "v_add_f32_dpp %[c5],  %[fv], %[t5]  row_ror:5  row_mask:0xf bank_mask:0xf\n\t"
    "v_add_f32_dpp %[c6],  %[fv], %[t6]  row_ror:6  row_mask:0xf bank_mask:0xf\n\t"
    "v_add_f32_dpp %[c7],  %[fv], %[t7]  row_ror:7  row_mask:0xf bank_mask:0xf\n\t"
    "v_add_f32_dpp %[c8],  %[fv], %[t8]  row_ror:8  row_mask:0xf bank_mask:0xf\n\t"
    "v_add_f32_dpp %[c9],  %[fv], %[t9]  row_ror:9  row_mask:0xf bank_mask:0xf\n\t"
    "v_add_f32_dpp %[c10], %[fv], %[t10] row_ror:10 row_mask:0xf bank_mask:0xf\n\t"
    "v_add_f32_dpp %[c11], %[fv], %[t11] row_ror:11 row_mask:0xf bank_mask:0xf\n\t"
    "v_add_f32_dpp %[c12], %[fv], %[t12] row_ror:12 row_mask:0xf bank_mask:0xf\n\t"
    "v_add_f32_dpp %[c13], %[fv], %[t13] row_ror:13 row_mask:0xf bank_mask:0xf\n\t"
    "v_add_f32_dpp %[c14], %[fv], %[t14] row_ror:14 row_mask:0xf bank_mask:0xf\n\t"
    "v_add_f32_dpp %[c15], %[fv], %[t15] row_ror:15 row_mask:0xf bank_mask:0xf\n\t"
    "v_max3_f32 %[c0],  %[c0],  %[c1],  %[c2]\n\t"
    "v_max3_f32 %[c3],  %[c3],  %[c4],  %[c5]\n\t"
    "v_max3_f32 %[c6],  %[c6],  %[c7],  %[c8]\n\t"
    "v_max3_f32 %[c9],  %[c9],  %[c10], %[c11]\n\t"
    "v_max3_f32 %[c12], %[c12], %[c13], %[c14]\n\t"
    "v_max3_f32 %[c0],  %[c0],  %[c3],  %[c6]\n\t"
    "v_max3_f32 %[c9],  %[c9],  %[c12], %[c15]\n\t"
    "v_max_f32 %[c0], %[c0], %[c9]\n\t"
    "v_add_f32 %[fv], %[c0], %[fb]\n\t"
    : [fv]"+v"(fvh),
      [c0]"=&v"(c0),  [c1]"=&v"(c1),  [c2]"=&v"(c2),  [c3]"=&v"(c3),
      [c4]"=&v"(c4),  [c5]"=&v"(c5),  [c6]"=&v"(c6),  [c7]"=&v"(c7),
      [c8]"=&v"(c8),  [c9]"=&v"(c9),  [c10]"=&v"(c10), [c11]"=&v"(c11),
      [c12]"=&v"(c12), [c13]"=&v"(c13), [c14]"=&v"(c14), [c15]"=&v"(c15)
    : [t0]"v"(t0), [t1]"v"(t1), [t2]"v"(t2), [t3]"v"(t3),
      [t4]"v"(t4), [t5]"v"(t5), [t6]"v"(t6), [t7]"v"(t7),
      [t8]"v"(t8), [t9]"v"(t9), [t10]"v"(t10), [t11]"v"(t11),
      [t12]"v"(t12), [t13]"v"(t13), [t14]"v"(t14), [t15]"v"(t15),
      [fb]"v"(fb));
  return fvh;
}

// ---------------------------------------------------------------------------
// K1: value-only exact Viterbi forward chain. ONE wave, forced-asm 16-rot
// step (1 cross-lane hop/step vs split-8's 3). All lanes hold fv[n]
// replicated; scalar imm-offset prefetch (r4-r12 scheme). Stores a 64B
// checkpoint every CSZ steps; k_fv regenerates FV in parallel.
// ---------------------------------------------------------------------------
__global__ __launch_bounds__(64)
void k_chain(const float* __restrict__ feats, const float* __restrict__ trans,
             float* __restrict__ CKPT, int* __restrict__ last_tag, int T) {
  const int l = threadIdx.x;
  const int n = l & 15;

  float tr[16];
  #pragma unroll
  for (int k = 0; k < 16; ++k) tr[k] = trans[n * 16 + ((n - k) & 15)];

  float fvh = 0.0f; // fv[n] = 0 initially

  float fbuf[PF];
  #pragma unroll
  for (int i = 0; i < PF; ++i) {
    int idx = i < T ? i : (T - 1);
    fbuf[i] = feats[(size_t)idx * 16 + n];
  }

  int t = 0;
  const int Tm = (T >= 2 * PF) ? ((T - PF) & ~(PF - 1)) : 0;
  for (; t < Tm; t += PF) {
    if ((t & (CSZ - 1)) == 0) CKPT[(size_t)(t >> CSB) * 16 + n] = fvh;
    const float* __restrict__ pf_ptr = feats + (size_t)(t + PF) * 16; // uniform
    #pragma unroll
    for (int u = 0; u < PF; ++u) {
      fvh = step16_asm(fvh, tr[0], tr[1], tr[2], tr[3], tr[4], tr[5], tr[6],
                       tr[7], tr[8], tr[9], tr[10], tr[11], tr[12], tr[13],
                       tr[14], tr[15], fbuf[u]);
      fbuf[u] = pf_ptr[u * 16 + n];   // imm-offset load, never OOB (t+u+PF <= T-1)
    }
  }
  for (; t < T; ++t) { // tail (< 2*PF steps): direct loads, cache-hot
    if ((t & (CSZ - 1)) == 0) CKPT[(size_t)(t >> CSB) * 16 + n] = fvh;
    fvh = step16_asm(fvh, tr[0], tr[1], tr[2], tr[3], tr[4], tr[5], tr[6],
                     tr[7], tr[8], tr[9], tr[10], tr[11], tr[12], tr[13],
                     tr[14], tr[15], feats[(size_t)t * 16 + n]);
  }

  // last_tag = argmax of final fv (first-index tie-break, ascending p).
  // Lanes 0-15 hold fv[n].
  float bv = __shfl(fvh, 0, 64); int bi = 0;
  #pragma unroll
  for (int p = 1; p < 16; ++p) {
    float ov = __shfl(fvh, p, 64);
    if (ov > bv) { bv = ov; bi = p; }
  }
  if (l == 0) *last_tag = bi;
}

// ---------------------------------------------------------------------------
// K1b: parallel FV regeneration. One wave per CSZ-step chunk; replays the
// identical fp32 recurrence from the chunk's checkpoint -> bit-exact FV.
// Throughput-bound (thousands of independent waves).
// ---------------------------------------------------------------------------
__global__ __launch_bounds__(256)
void k_fv(const float* __restrict__ CKPT, const float* __restrict__ trans,
          const float* __restrict__ feats, float* __restrict__ FV, int T, int NC) {
  const int tid = threadIdx.x;
  const int wid = blockIdx.x * 4 + (tid >> 6);
  const int l = tid & 63;
  const int n = l & 15;
  if (wid >= NC) return;

  float trr[16];
  #pragma unroll
  for (int k = 0; k < 16; ++k) trr[k] = trans[n * 16 + ((n - k) & 15)];

  float fv = CKPT[(size_t)wid * 16 + n];
  const int a = wid * CSZ;
  int b = a + CSZ; if (b > T) b = T;
  for (int t = a; t < b; ++t) {
    FV[(size_t)t * 16 + n] = fv;            // FV[t] = fv entering step t
    fv = vstep(fv, trr) + feats[(size_t)t * 16 + n];
  }
}

// ---------------------------------------------------------------------------
// K2: parallel backpointer recompute. Thread per t.
// bp[t][n] = argmax_p fl(FV[t][p] + tr[n][p]), strict-> scan (first-max),
// bit-identical to the reference's jnp.argmax(scores, axis=1).
// ---------------------------------------------------------------------------
__global__ __launch_bounds__(256)
void k_bp(const float* __restrict__ FV, const float* __restrict__ trans,
          uint4* __restrict__ bp, int T) {
  __shared__ float str[256];
  const int tid = threadIdx.x;
  str[tid] = trans[tid];
  __syncthreads();
  const int t = blockIdx.x * blockDim.x + tid;
  if (t >= T) return;
  const float4* fr = (const float4*)(FV + (size_t)t * 16);
  float4 q0 = fr[0], q1 = fr[1], q2 = fr[2], q3 = fr[3];
  float fv[16] = {q0.x, q0.y, q0.z, q0.w, q1.x, q1.y, q1.z, q1.w,
                  q2.x, q2.y, q2.z, q2.w, q3.x, q3.y, q3.z, q3.w};
  uint32_t w[4];
  #pragma unroll
  for (int g = 0; g < 4; ++g) {
    uint32_t word = 0;
    #pragma unroll
    for (int s = 0; s < 4; ++s) {
      const int nn = 4 * g + s;
      float best = fv[0] + str[nn * 16 + 0];
      int bi = 0;
      #pragma unroll
      for (int p = 1; p < 16; ++p) {
        float v = fv[p] + str[nn * 16 + p];
        if (v > best) { best = v; bi = p; }
      }
      word |= (uint32_t)bi << (8 * s);
    }
    w[g] = word;
  }
  bp[t] = make_uint4(w[0], w[1], w[2], w[3]);
}

// ---------------------------------------------------------------------------
// K3: per-chunk 16-hypothesis backtrack (exact integer pointer chase).
// ---------------------------------------------------------------------------
__global__ __launch_bounds__(64)
void k_chase(const unsigned char* __restrict__ bp, unsigned char* __restrict__ st,
             unsigned char* __restrict__ maps, int T, int C) {
  const int tid = threadIdx.x;
  const int chunk = blockIdx.x * 4 + (tid >> 4);
  const int h = tid & 15;
  if (chunk >= C) return;
  const int a = chunk * L4;
  int b = a + L4; if (b > T) b = T;
  int cur = h;
  for (int t = b - 1; t >= a; --t) {
    cur = bp[(size_t)t * 16 + cur];
    st[(size_t)t * 16 + h] = (unsigned char)cur;
  }
  maps[chunk * 16 + h] = (unsigned char)cur;
}

// ---------------------------------------------------------------------------
// K4: compose GRP consecutive chunk maps into one super-map per group.
// ---------------------------------------------------------------------------
__global__ __launch_bounds__(64)
void k_group(const unsigned char* __restrict__ maps, unsigned char* __restrict__ sup,
             int C, int NG) {
  const int g = blockIdx.x;
  const int e = threadIdx.x;
  if (g >= NG || e >= 16) return;
  int hi = g * GRP + GRP - 1; if (hi > C - 1) hi = C - 1;
  int cur = e;
  for (int c = hi; c >= g * GRP; --c) cur = maps[c * 16 + cur];
  sup[g * 16 + e] = (unsigned char)cur;
}

// ---------------------------------------------------------------------------
// K5: resolve true tag at every chunk's end boundary.
// ---------------------------------------------------------------------------
__global__ __launch_bounds__(128)
void k_resolve(const unsigned char* __restrict__ maps, const unsigned char* __restrict__ sup,
               const int* __restrict__ last_tag, unsigned char* __restrict__ s_arr,
               int C, int NG) {
  __shared__ unsigned char Sg[4096];
  const int tid = threadIdx.x;
  if (tid == 0) {
    int cur = *last_tag;
    for (int g = NG - 1; g >= 0; --g) {
      Sg[g] = (unsigned char)cur;
      cur = sup[g * 16 + cur];
    }
  }
  __syncthreads();
  for (int g = tid; g < NG; g += blockDim.x) {
    int cur = Sg[g];
    int hi = g * GRP + GRP - 1; if (hi > C - 1) hi = C - 1;
    for (int c = hi; c >= g * GRP; --c) {
      s_arr[c] = (unsigned char)cur;
      cur = maps[c * 16 + cur];
    }
  }
}

// ---------------------------------------------------------------------------
// K6: emit out[t] = st[t*16 + s_arr[t / L4]] as int32.
// ---------------------------------------------------------------------------
__global__ void k_emit(const unsigned char* __restrict__ st,
                       const unsigned char* __restrict__ s_arr,
                       int* __restrict__ out, int T) {
  int t = blockIdx.x * blockDim.x + threadIdx.x;
  if (t < T) out[t] = (int)st[(size_t)t * 16 + s_arr[t / L4]];
}

extern "C" void kernel_launch(void* const* d_in, const int* in_sizes, int n_in,
                              void* d_out, int out_size, void* d_ws, size_t ws_size,
                              hipStream_t stream) {
  const float* feats = (const float*)d_in[0];   // [1, T, 16] fp32
  const float* trans = (const float*)d_in[1];   // [16, 16]  fp32
  int* out = (int*)d_out;                       // [T] int32

  const int T  = in_sizes[0] / 16;
  const int C  = (T + L4 - 1) / L4;
  const int NG = (C + GRP - 1) / GRP;
  const int NC = (T + CSZ - 1) / CSZ;

  char* ws = (char*)d_ws;
  float* FV           = (float*)ws;                           // (T+1)*16 floats
  float* CKPT         = FV + (size_t)(T + 1) * 16;            // NC*16 floats
  unsigned char* bp   = (unsigned char*)(CKPT + (size_t)NC * 16); // T*16 B, 16B-aligned
  unsigned char* st   = bp + (size_t)T * 16;                  // T*16 B
  unsigned char* maps = st + (size_t)T * 16;                  // C*16
  unsigned char* sup  = maps + (size_t)C * 16;                // NG*16
  unsigned char* sarr = sup + (size_t)NG * 16;                // C
  int* last_tag = (int*)(((uintptr_t)(sarr + C) + 15) & ~(uintptr_t)15);
  size_t need = (size_t)((char*)(last_tag + 1) - ws);
  if (ws_size < need) return;  // insufficient scratch -> fail visibly

  k_chain<<<1, 64, 0, stream>>>(feats, trans, CKPT, last_tag, T);
  k_fv<<<(NC + 3) / 4, 256, 0, stream>>>(CKPT, trans, feats, FV, T, NC);
  k_bp<<<(T + 255) / 256, 256, 0, stream>>>(FV, trans, (uint4*)bp, T);
  k_chase<<<(C + 3) / 4, 64, 0, stream>>>(bp, st, maps, T, C);
  k_group<<<NG, 64, 0, stream>>>(maps, sup, C, NG);
  k_resolve<<<1, 128, 0, stream>>>(maps, sup, last_tag, sarr, C, NG);
  const int thr = 256;
  k_emit<<<(T + thr - 1) / thr, thr, 0, stream>>>(st, sarr, out, T);
}

// Round 14
// 42631.769 us; speedup vs baseline: 1.1724x; 1.1724x over previous
//
#include <hip/hip_runtime.h>
#include <stdint.h>

#define L4   250   // chase chunk length
#define GRP  50    // chunks per map-composition group
#define PF   32    // feat prefetch depth in k_chain
#define CSZ  256   // checkpoint interval (power of 2)
#define CSB  8     // log2(CSZ)

// DPP row_ror:K — dst lane i reads src lane (i-K)&15 within its row of 16.
// Direction HW-validated bit-exact (absmax 0) in prior rounds.
template<int K>
__device__ __forceinline__ float rotr(float x) {
  return __int_as_float(__builtin_amdgcn_mov_dpp(__float_as_int(x), 0x120 + K, 0xF, 0xF, false));
}

// Full 16-candidate exact step (used by throughput kernel k_fv).
// Lane layout: n = lane&15, lane holds fv[n]; trr[k] = tr[n][(n-k)&15].
// fp32 max over 16 finite values is order-independent -> bit-identical to
// the reference's jnp.max regardless of tree shape.
__device__ __forceinline__ float vstep(float fv, const float* __restrict__ trr) {
  float c0  = fv           + trr[0];
  float c1  = rotr<1 >(fv) + trr[1];
  float c2  = rotr<2 >(fv) + trr[2];
  float c3  = rotr<3 >(fv) + trr[3];
  float c4  = rotr<4 >(fv) + trr[4];
  float c5  = rotr<5 >(fv) + trr[5];
  float c6  = rotr<6 >(fv) + trr[6];
  float c7  = rotr<7 >(fv) + trr[7];
  float c8  = rotr<8 >(fv) + trr[8];
  float c9  = rotr<9 >(fv) + trr[9];
  float c10 = rotr<10>(fv) + trr[10];
  float c11 = rotr<11>(fv) + trr[11];
  float c12 = rotr<12>(fv) + trr[12];
  float c13 = rotr<13>(fv) + trr[13];
  float c14 = rotr<14>(fv) + trr[14];
  float c15 = rotr<15>(fv) + trr[15];
  float t0 = fmaxf(fmaxf(c0,  c1),  c2);
  float t1 = fmaxf(fmaxf(c3,  c4),  c5);
  float t2 = fmaxf(fmaxf(c6,  c7),  c8);
  float t3 = fmaxf(fmaxf(c9,  c10), c11);
  float t4 = fmaxf(fmaxf(c12, c13), c14);
  float u0 = fmaxf(fmaxf(t0, t1), t2);
  float u1 = fmaxf(fmaxf(t3, t4), c15);
  return fmaxf(u0, u1);
}

// Split 8-candidate exact step — SINGLE inline-asm block (r12, best measured:
// 102 cy/step / 42.4 ms). r13 proved the 16-rot asm alternative is worse
// (119 cy: issue slots cost ~2.4 cy, dependent hops ~9 cy, no cross-lane
// premium); r8+r11 proved two-block splits cost ~10%. This structure is
// final: 18 slots, 7 dependent hops — at the solo-wave latency floor.
// Math bit-identical to r4-r12 (absmax 0, eight rounds):
//   lane (h,n) holds fvh = fv[nid], nid = n ^ (8h);
//   c_i = row_ror:i(fvh) + trr[i] = fv[(nid-i)&15] + tr[n][(nid-i)&15];
//   union over h,i = all 16 p exactly once; 16-way fp32 max is
//   order-independent; permlane32_swap merges halves ((m,mc)-equal trick:
//   any half-exchange pairing of two equal registers gives
//   max(m[l], m[l^32]) after the final max); tail: plain add (lo half) +
//   masked add_dpp row_ror:8 row_mask:0xC (hi half) — fused
//   redistribute+feat-add, M-write hazard covered by the interposed add.
// Hazards: prev-step fv write -> c1 DPP read covered by interposed c0 add;
// mc write -> permlane read covered by s_nop 1; M write -> add_dpp DPP read
// covered by the interposed plain v_add_f32.
__device__ __forceinline__ float step8_asm(float fvh,
    float t0, float t1, float t2, float t3,
    float t4, float t5, float t6, float t7, float fb) {
  float c0, c1, c2, c3, c4, c5, c6, c7, a, b, w, m, mc, M;
  asm volatile(
    "v_add_f32 %[c0], %[fv], %[t0]\n\t"
    "v_add_f32_dpp %[c1], %[fv], %[t1] row_ror:1 row_mask:0xf bank_mask:0xf\n\t"
    "v_add_f32_dpp %[c2], %[fv], %[t2] row_ror:2 row_mask:0xf bank_mask:0xf\n\t"
    "v_add_f32_dpp %[c3], %[fv], %[t3] row_ror:3 row_mask:0xf bank_mask:0xf\n\t"
    "v_add_f32_dpp %[c4], %[fv], %[t4] row_ror:4 row_mask:0xf bank_mask:0xf\n\t"
    "v_add_f32_dpp %[c5], %[fv], %[t5] row_ror:5 row_mask:0xf bank_mask:0xf\n\t"
    "v_add_f32_dpp %[c6], %[fv], %[t6] row_ror:6 row_mask:0xf bank_mask:0xf\n\t"
    "v_add_f32_dpp %[c7], %[fv], %[t7] row_ror:7 row_mask:0xf bank_mask:0xf\n\t"
    "v_max3_f32 %[a], %[c0], %[c1], %[c2]\n\t"
    "v_max3_f32 %[b], %[c3], %[c4], %[c5]\n\t"
    "v_max_f32 %[w], %[c6], %[c7]\n\t"
    "v_max3_f32 %[m], %[a], %[b], %[w]\n\t"
    "v_max3_f32 %[mc], %[a], %[b], %[w]\n\t"
    "s_nop 1\n\t"
    "v_permlane32_swap_b32 %[m], %[mc]\n\t"
    "v_max_f32 %[M], %[m], %[mc]\n\t"
    "v_add_f32 %[fv], %[M], %[fb]\n\t"
    "v_add_f32_dpp %[fv], %[M], %[fb] row_ror:8 row_mask:0xc bank_mask:0xf\n\t"
    : [fv]"+v"(fvh),
      [c0]"=&v"(c0), [c1]"=&v"(c1), [c2]"=&v"(c2), [c3]"=&v"(c3),
      [c4]"=&v"(c4), [c5]"=&v"(c5), [c6]"=&v"(c6), [c7]"=&v"(c7),
      [a]"=&v"(a), [b]"=&v"(b), [w]"=&v"(w), [m]"=&v"(m),
      [mc]"=&v"(mc), [M]"=&v"(M)
    : [t0]"v"(t0), [t1]"v"(t1), [t2]"v"(t2), [t3]"v"(t3),
      [t4]"v"(t4), [t5]"v"(t5), [t6]"v"(t6), [t7]"v"(t7), [fb]"v"(fb));
  return fvh;
}

// ---------------------------------------------------------------------------
// K1: value-only exact Viterbi forward chain. ONE wave, r12 structure
// (single asm block, compiler-scheduled scalar imm-offset prefetch around it).
// Stores a 64B checkpoint every CSZ steps; k_fv regenerates FV in parallel.
// ---------------------------------------------------------------------------
__global__ __launch_bounds__(64)
void k_chain(const float* __restrict__ feats, const float* __restrict__ trans,
             float* __restrict__ CKPT, int* __restrict__ last_tag, int T) {
  const int l = threadIdx.x;
  const int n = l & 15;
  const int nid = n ^ ((l & 32) ? 8 : 0);

  float tr0 = trans[n * 16 + ((nid - 0) & 15)];
  float tr1 = trans[n * 16 + ((nid - 1) & 15)];
  float tr2 = trans[n * 16 + ((nid - 2) & 15)];
  float tr3 = trans[n * 16 + ((nid - 3) & 15)];
  float tr4 = trans[n * 16 + ((nid - 4) & 15)];
  float tr5 = trans[n * 16 + ((nid - 5) & 15)];
  float tr6 = trans[n * 16 + ((nid - 6) & 15)];
  float tr7 = trans[n * 16 + ((nid - 7) & 15)];

  float fvh = 0.0f; // fv[nid] = 0 initially

  float fbuf[PF];
  #pragma unroll
  for (int i = 0; i < PF; ++i) {
    int idx = i < T ? i : (T - 1);
    fbuf[i] = feats[(size_t)idx * 16 + nid];
  }

  int t = 0;
  const int Tm = (T >= 2 * PF) ? ((T - PF) & ~(PF - 1)) : 0;
  for (; t < Tm; t += PF) {
    if ((t & (CSZ - 1)) == 0) CKPT[(size_t)(t >> CSB) * 16 + nid] = fvh;
    const float* __restrict__ pf_ptr = feats + (size_t)(t + PF) * 16; // uniform
    #pragma unroll
    for (int u = 0; u < PF; ++u) {
      fvh = step8_asm(fvh, tr0, tr1, tr2, tr3, tr4, tr5, tr6, tr7, fbuf[u]);
      fbuf[u] = pf_ptr[u * 16 + nid];   // imm-offset load, never OOB (t+u+PF <= T-1)
    }
  }
  for (; t < T; ++t) { // tail (< 2*PF steps): direct loads, cache-hot
    if ((t & (CSZ - 1)) == 0) CKPT[(size_t)(t >> CSB) * 16 + nid] = fvh;
    fvh = step8_asm(fvh, tr0, tr1, tr2, tr3, tr4, tr5, tr6, tr7,
                    feats[(size_t)t * 16 + nid]);
  }

  // last_tag = argmax of final fv (first-index tie-break, ascending p).
  // Lanes 0-15 (lo half) hold unshifted fv[n].
  float bv = __shfl(fvh, 0, 64); int bi = 0;
  #pragma unroll
  for (int p = 1; p < 16; ++p) {
    float ov = __shfl(fvh, p, 64);
    if (ov > bv) { bv = ov; bi = p; }
  }
  if (l == 0) *last_tag = bi;
}

// ---------------------------------------------------------------------------
// K1b: parallel FV regeneration. One wave per CSZ-step chunk; replays the
// identical fp32 recurrence from the chunk's checkpoint -> bit-exact FV.
// Throughput-bound (thousands of independent waves).
// ---------------------------------------------------------------------------
__global__ __launch_bounds__(256)
void k_fv(const float* __restrict__ CKPT, const float* __restrict__ trans,
          const float* __restrict__ feats, float* __restrict__ FV, int T, int NC) {
  const int tid = threadIdx.x;
  const int wid = blockIdx.x * 4 + (tid >> 6);
  const int l = tid & 63;
  const int n = l & 15;
  if (wid >= NC) return;

  float trr[16];
  #pragma unroll
  for (int k = 0; k < 16; ++k) trr[k] = trans[n * 16 + ((n - k) & 15)];

  float fv = CKPT[(size_t)wid * 16 + n];
  const int a = wid * CSZ;
  int b = a + CSZ; if (b > T) b = T;
  for (int t = a; t < b; ++t) {
    FV[(size_t)t * 16 + n] = fv;            // FV[t] = fv entering step t
    fv = vstep(fv, trr) + feats[(size_t)t * 16 + n];
  }
}

// ---------------------------------------------------------------------------
// K2: parallel backpointer recompute. Thread per t.
// bp[t][n] = argmax_p fl(FV[t][p] + tr[n][p]), strict-> scan (first-max),
// bit-identical to the reference's jnp.argmax(scores, axis=1).
// ---------------------------------------------------------------------------
__global__ __launch_bounds__(256)
void k_bp(const float* __restrict__ FV, const float* __restrict__ trans,
          uint4* __restrict__ bp, int T) {
  __shared__ float str[256];
  const int tid = threadIdx.x;
  str[tid] = trans[tid];
  __syncthreads();
  const int t = blockIdx.x * blockDim.x + tid;
  if (t >= T) return;
  const float4* fr = (const float4*)(FV + (size_t)t * 16);
  float4 q0 = fr[0], q1 = fr[1], q2 = fr[2], q3 = fr[3];
  float fv[16] = {q0.x, q0.y, q0.z, q0.w, q1.x, q1.y, q1.z, q1.w,
                  q2.x, q2.y, q2.z, q2.w, q3.x, q3.y, q3.z, q3.w};
  uint32_t w[4];
  #pragma unroll
  for (int g = 0; g < 4; ++g) {
    uint32_t word = 0;
    #pragma unroll
    for (int s = 0; s < 4; ++s) {
      const int nn = 4 * g + s;
      float best = fv[0] + str[nn * 16 + 0];
      int bi = 0;
      #pragma unroll
      for (int p = 1; p < 16; ++p) {
        float v = fv[p] + str[nn * 16 + p];
        if (v > best) { best = v; bi = p; }
      }
      word |= (uint32_t)bi << (8 * s);
    }
    w[g] = word;
  }
  bp[t] = make_uint4(w[0], w[1], w[2], w[3]);
}

// ---------------------------------------------------------------------------
// K3: per-chunk 16-hypothesis backtrack (exact integer pointer chase).
// ---------------------------------------------------------------------------
__global__ __launch_bounds__(64)
void k_chase(const unsigned char* __restrict__ bp, unsigned char* __restrict__ st,
             unsigned char* __restrict__ maps, int T, int C) {
  const int tid = threadIdx.x;
  const int chunk = blockIdx.x * 4 + (tid >> 4);
  const int h = tid & 15;
  if (chunk >= C) return;
  const int a = chunk * L4;
  int b = a + L4; if (b > T) b = T;
  int cur = h;
  for (int t = b - 1; t >= a; --t) {
    cur = bp[(size_t)t * 16 + cur];
    st[(size_t)t * 16 + h] = (unsigned char)cur;
  }
  maps[chunk * 16 + h] = (unsigned char)cur;
}

// ---------------------------------------------------------------------------
// K4: compose GRP consecutive chunk maps into one super-map per group.
// ---------------------------------------------------------------------------
__global__ __launch_bounds__(64)
void k_group(const unsigned char* __restrict__ maps, unsigned char* __restrict__ sup,
             int C, int NG) {
  const int g = blockIdx.x;
  const int e = threadIdx.x;
  if (g >= NG || e >= 16) return;
  int hi = g * GRP + GRP - 1; if (hi > C - 1) hi = C - 1;
  int cur = e;
  for (int c = hi; c >= g * GRP; --c) cur = maps[c * 16 + cur];
  sup[g * 16 + e] = (unsigned char)cur;
}

// ---------------------------------------------------------------------------
// K5: resolve true tag at every chunk's end boundary.
// ---------------------------------------------------------------------------
__global__ __launch_bounds__(128)
void k_resolve(const unsigned char* __restrict__ maps, const unsigned char* __restrict__ sup,
               const int* __restrict__ last_tag, unsigned char* __restrict__ s_arr,
               int C, int NG) {
  __shared__ unsigned char Sg[4096];
  const int tid = threadIdx.x;
  if (tid == 0) {
    int cur = *last_tag;
    for (int g = NG - 1; g >= 0; --g) {
      Sg[g] = (unsigned char)cur;
      cur = sup[g * 16 + cur];
    }
  }
  __syncthreads();
  for (int g = tid; g < NG; g += blockDim.x) {
    int cur = Sg[g];
    int hi = g * GRP + GRP - 1; if (hi > C - 1) hi = C - 1;
    for (int c = hi; c >= g * GRP; --c) {
      s_arr[c] = (unsigned char)cur;
      cur = maps[c * 16 + cur];
    }
  }
}

// ---------------------------------------------------------------------------
// K6: emit out[t] = st[t*16 + s_arr[t / L4]] as int32.
// ---------------------------------------------------------------------------
__global__ void k_emit(const unsigned char* __restrict__ st,
                       const unsigned char* __restrict__ s_arr,
                       int* __restrict__ out, int T) {
  int t = blockIdx.x * blockDim.x + threadIdx.x;
  if (t < T) out[t] = (int)st[(size_t)t * 16 + s_arr[t / L4]];
}

extern "C" void kernel_launch(void* const* d_in, const int* in_sizes, int n_in,
                              void* d_out, int out_size, void* d_ws, size_t ws_size,
                              hipStream_t stream) {
  const float* feats = (const float*)d_in[0];   // [1, T, 16] fp32
  const float* trans = (const float*)d_in[1];   // [16, 16]  fp32
  int* out = (int*)d_out;                       // [T] int32

  const int T  = in_sizes[0] / 16;
  const int C  = (T + L4 - 1) / L4;
  const int NG = (C + GRP - 1) / GRP;
  const int NC = (T + CSZ - 1) / CSZ;

  char* ws = (char*)d_ws;
  float* FV           = (float*)ws;                           // (T+1)*16 floats
  float* CKPT         = FV + (size_t)(T + 1) * 16;            // NC*16 floats
  unsigned char* bp   = (unsigned char*)(CKPT + (size_t)NC * 16); // T*16 B, 16B-aligned
  unsigned char* st   = bp + (size_t)T * 16;                  // T*16 B
  unsigned char* maps = st + (size_t)T * 16;                  // C*16
  unsigned char* sup  = maps + (size_t)C * 16;                // NG*16
  unsigned char* sarr = sup + (size_t)NG * 16;                // C
  int* last_tag = (int*)(((uintptr_t)(sarr + C) + 15) & ~(uintptr_t)15);
  size_t need = (size_t)((char*)(last_tag + 1) - ws);
  if (ws_size < need) return;  // insufficient scratch -> fail visibly

  k_chain<<<1, 64, 0, stream>>>(feats, trans, CKPT, last_tag, T);
  k_fv<<<(NC + 3) / 4, 256, 0, stream>>>(CKPT, trans, feats, FV, T, NC);
  k_bp<<<(T + 255) / 256, 256, 0, stream>>>(FV, trans, (uint4*)bp, T);
  k_chase<<<(C + 3) / 4, 64, 0, stream>>>(bp, st, maps, T, C);
  k_group<<<NG, 64, 0, stream>>>(maps, sup, C, NG);
  k_resolve<<<1, 128, 0, stream>>>(maps, sup, last_tag, sarr, C, NG);
  const int thr = 256;
  k_emit<<<(T + thr - 1) / thr, thr, 0, stream>>>(st, sarr, out, T);
}